// Round 7
// baseline (321.601 us; speedup 1.0000x reference)
//
#include <hip/hip_runtime.h>
#include <hip/hip_fp16.h>

// VQ codebook quantization, MI355X. Two-phase argmin:
//   prep:   fp32 -> bf16 repack of z and embedding into MFMA *fragment* layout
//           ([group16][kstep][lane], 1KB frags) + row norms. Wave = 2 rows
//           (8 elems/lane x 32 lanes per row).
//   pass A: barrier-free, LDS-free bf16 MFMA. Wave = 64 codes x 512 rows;
//           A-fragments live in registers (areg[8][4]); B-fragments stream
//           from global (coalesced 1KB loads) interleaved with MFMA.
//           Output: per-(row, 16-code-window) minima, fp16, tm[n][row][512].
//   pass B: wave-per-2-rows exact fp32 rescore of flagged windows (reference
//           combine + lowest-k ties), fused gather + commitment loss.
// B=8192, d_latent=512, ncb=2, K=8192, d_sub=256.

#define KCODES 8192
#define DSUB   256
#define BROWS  8192
#define NROWS  16384
#define NWIN   512            // 16-code windows per codebook

#define QUANT_N  (BROWS * 512)
#define IDX_OFF  QUANT_N
#define LOSS_OFF (QUANT_N + NROWS)

// ws layout (bytes)
#define WS_ESQ    0          // 16384 f32
#define WS_ZSQ    65536      // 16384 f32
#define WS_COUNTS 196608     // 16384 i32 (zeroed)
#define WS_LOSS   262144     // 1 f32 (zeroed)
#define WS_ZBF    1048576    // [2][8192][256] bf16 = 8 MB, fragment layout
#define WS_EBF    9437184    // [2][8192][256] bf16 = 8 MB, fragment layout
#define WS_TM     17825792   // [2][8192][512] fp16 = 16 MB (window = 16 codes)

#define EPS 2.5e-4f

// Fragment layout (elements, per codebook): row r, element k ->
//   (r>>4)*4096 + (k>>5)*512 + ((k>>3)&3)*128 + (r&15)*8 + (k&7)
// A wave's 16-row x 32-elem fragment chunk is 1KB contiguous at lane*8,
// lane = (quad<<4)|c16, matching mfma_f32_16x16x32_bf16 A/B fragments.

typedef __attribute__((ext_vector_type(8))) short short8;
typedef __attribute__((ext_vector_type(8))) unsigned short ushort8v;
typedef __attribute__((ext_vector_type(4))) float floatx4;

__device__ inline unsigned short f2bf(float f) {
  unsigned u = __float_as_uint(f);
  return (unsigned short)((u + 0x7FFFu + ((u >> 16) & 1u)) >> 16);
}

// ------------------------------------------------------------ prep kernel
// 2048 blocks x 256; each wave handles a row PAIR per iteration:
// lane l -> row base+(l>>5), elements (l&31)*8 .. +8  (32 lanes x 8 = 256).
__global__ void prep_kernel(const float* __restrict__ z, const float* __restrict__ e,
                            float* __restrict__ e_sq, float* __restrict__ z_sq,
                            unsigned short* __restrict__ zbf, unsigned short* __restrict__ ebf) {
  int gw  = blockIdx.x * 4 + (threadIdx.x >> 6);  // 0..8191
  int l   = threadIdx.x & 63;
  int sub = l >> 5;                               // row within pair
  int l32 = l & 31;                               // element-chunk within row
  for (int i = 0; i < 2; ++i) {
    int row = i * 16384 + gw * 2 + sub;           // 0..32767 (i=0: emb, i=1: z)
    const float* src;
    unsigned short* dst;
    int r;                                        // row index in dst space
    float* sq;
    int sqi;
    if (row < NROWS) {
      src = e + (size_t)row * DSUB;
      dst = ebf; r = row; sq = e_sq; sqi = row;
    } else {
      int rz = row - NROWS;                       // z flat row = b*2+n
      int n = rz & 1, b = rz >> 1;
      src = z + (size_t)rz * DSUB;
      dst = zbf + (size_t)n * 2097152; r = b; sq = z_sq; sqi = rz;
    }
    float4 v0 = ((const float4*)src)[2 * l32];
    float4 v1 = ((const float4*)src)[2 * l32 + 1];
    ushort8v o;
    o[0] = f2bf(v0.x); o[1] = f2bf(v0.y); o[2] = f2bf(v0.z); o[3] = f2bf(v0.w);
    o[4] = f2bf(v1.x); o[5] = f2bf(v1.y); o[6] = f2bf(v1.z); o[7] = f2bf(v1.w);
    // k = l32*8: k>>5 = l32>>2, (k>>3)&3 = l32&3, k&7 = 0..7
    size_t off = (size_t)(r >> 4) * 4096 + (l32 >> 2) * 512 + (l32 & 3) * 128 + (r & 15) * 8;
    *(ushort8v*)(dst + off) = o;
    float s = v0.x * v0.x + v0.y * v0.y + v0.z * v0.z + v0.w * v0.w
            + v1.x * v1.x + v1.y * v1.y + v1.z * v1.z + v1.w * v1.w;
    #pragma unroll
    for (int off2 = 16; off2; off2 >>= 1) s += __shfl_down(s, off2, 32);
    if (l32 == 0) sq[sqi] = s;
  }
}

// ------------------------------------------------------------ pass A (MFMA)
// Grid (32, 16, 2), 256 threads. Wave = 64 codes (blk.x*256 + w*64) x 512 rows
// (blk.y*512, 8 tiles of 64). No LDS, no barriers. A-frags in registers.
__global__ __launch_bounds__(256, 2)
void passA_kernel(const unsigned short* __restrict__ zbf, const unsigned short* __restrict__ ebf,
                  const float* __restrict__ e_sq, __half* __restrict__ tm) {
  const int n    = blockIdx.z;
  const int w    = threadIdx.x >> 6, lane = threadIdx.x & 63;
  const int quad = lane >> 4, c16 = lane & 15;
  const int cb   = blockIdx.x * 256 + w * 64;     // wave's code base
  const int rg   = blockIdx.y * 512;              // wave's row base

  const unsigned short* en = ebf + (size_t)n * 2097152;
  const unsigned short* zn = zbf + (size_t)n * 2097152;
  const float* esq = e_sq + n * KCODES;
  __half* tmn = tm + (size_t)n * (BROWS * NWIN);

  // A fragments: 64 codes x 256 dims, 8 k-steps x 4 mf, 1KB coalesced each.
  short8 areg[8][4];
  #pragma unroll
  for (int k0 = 0; k0 < 8; ++k0)
    #pragma unroll
    for (int mf = 0; mf < 4; ++mf)
      areg[k0][mf] = *(const short8*)(en + (size_t)((cb >> 4) + mf) * 4096 + k0 * 512 + lane * 8);

  float eq[4][4];
  #pragma unroll
  for (int mf = 0; mf < 4; ++mf) {
    int kb = cb + mf * 16 + quad * 4;
    #pragma unroll
    for (int i = 0; i < 4; ++i) eq[mf][i] = esq[kb + i];
  }

  for (int nt = 0; nt < 8; ++nt) {
    const int rowbase = rg + nt * 64;

    floatx4 acc[4][4];
    #pragma unroll
    for (int i = 0; i < 4; ++i)
      #pragma unroll
      for (int j = 0; j < 4; ++j) acc[i][j] = (floatx4){0.f, 0.f, 0.f, 0.f};

    #pragma unroll
    for (int k0 = 0; k0 < 8; ++k0) {
      short8 b[4];
      #pragma unroll
      for (int nf = 0; nf < 4; ++nf)
        b[nf] = *(const short8*)(zn + (size_t)((rowbase >> 4) + nf) * 4096 + k0 * 512 + lane * 8);
      #pragma unroll
      for (int mf = 0; mf < 4; ++mf)
        #pragma unroll
        for (int nf = 0; nf < 4; ++nf)
          acc[mf][nf] = __builtin_amdgcn_mfma_f32_16x16x32_bf16(areg[k0][mf], b[nf], acc[mf][nf], 0, 0, 0);
    }

    // epilogue: per-mf (16-code window) min of e_sq[k] - 2*c, per z-row column
    #pragma unroll
    for (int nf = 0; nf < 4; ++nf) {
      float vm[4];
      #pragma unroll
      for (int mf = 0; mf < 4; ++mf) {
        float v = eq[mf][0] - 2.0f * acc[mf][nf][0];
        v = fminf(v, eq[mf][1] - 2.0f * acc[mf][nf][1]);
        v = fminf(v, eq[mf][2] - 2.0f * acc[mf][nf][2]);
        v = fminf(v, eq[mf][3] - 2.0f * acc[mf][nf][3]);
        v = fminf(v, __shfl_xor(v, 16, 64));
        v = fminf(v, __shfl_xor(v, 32, 64));
        vm[mf] = v;
      }
      if (quad == 0) {
        int zr = rowbase + nf * 16 + c16;
        ushort4 o;
        o.x = __half_as_ushort(__float2half(vm[0]));
        o.y = __half_as_ushort(__float2half(vm[1]));
        o.z = __half_as_ushort(__float2half(vm[2]));
        o.w = __half_as_ushort(__float2half(vm[3]));
        *(ushort4*)&tmn[(size_t)zr * NWIN + (cb >> 4)] = o;
      }
    }
  }
}

// ------------------------------------------------------------ pass B (exact + gather)
// 2048 blocks x 4 waves; each WAVE owns 2 rows, no __syncthreads.
__global__ __launch_bounds__(256)
void passB_kernel(const float* __restrict__ z, const float* __restrict__ emb,
                  const float* __restrict__ e_sq, const float* __restrict__ z_sq,
                  const __half* __restrict__ tm, float* __restrict__ out,
                  int* __restrict__ counts, float* __restrict__ loss) {
  const int w    = threadIdx.x >> 6, lane = threadIdx.x & 63;
  const int gw   = blockIdx.x * 4 + w;  // 0..8191
  const int q    = lane & 3;            // dim-quarter within code group
  const int g    = lane >> 2;           // code group 0..15
  float lossacc  = 0.f;

  for (int i = 0; i < 2; ++i) {
    const int row = gw * 2 + i;         // rz = b*2 + n
    const int n = row & 1, b = row >> 1;
    const float* ebase = emb + (size_t)n * KCODES * DSUB;
    const float* esq   = e_sq + n * KCODES;

    // threshold from tm row (8 fp16 per lane)
    const __half* tmr = tm + ((size_t)n * BROWS + b) * NWIN;
    uint4 tq = *(const uint4*)(tmr + lane * 8);
    float t[8];
    {
      __half2 h;
      h = *(__half2*)&tq.x; t[0] = __low2float(h); t[1] = __high2float(h);
      h = *(__half2*)&tq.y; t[2] = __low2float(h); t[3] = __high2float(h);
      h = *(__half2*)&tq.z; t[4] = __low2float(h); t[5] = __high2float(h);
      h = *(__half2*)&tq.w; t[6] = __low2float(h); t[7] = __high2float(h);
    }
    float mv = t[0];
    #pragma unroll
    for (int j = 1; j < 8; ++j) mv = fminf(mv, t[j]);
    #pragma unroll
    for (int off = 32; off; off >>= 1) mv = fminf(mv, __shfl_xor(mv, off, 64));
    const float thr = mv + EPS;
    const float zsr = z_sq[row];

    float bestd = 3.4e38f;
    int   bestk = 0x7fffffff;
    #pragma unroll
    for (int j = 0; j < 8; ++j) {
      unsigned long long mbits = __ballot(t[j] <= thr);
      while (mbits) {
        int src = __ffsll(mbits) - 1;
        mbits &= mbits - 1;
        int win  = src * 8 + j;
        int code = win * 16 + g;        // this group's code in the window
        const float4* ep = (const float4*)(ebase + (size_t)code * DSUB + q * 64);
        const float4* zp = (const float4*)(z + (size_t)row * DSUB + q * 64);
        float s = 0.f;
        #pragma unroll
        for (int u = 0; u < 16; ++u) {
          float4 ev = ep[u], zv = zp[u];
          s += ev.x * zv.x; s += ev.y * zv.y; s += ev.z * zv.z; s += ev.w * zv.w;
        }
        s += __shfl_xor(s, 1, 64);
        s += __shfl_xor(s, 2, 64);
        float dist = (zsr - 2.0f * s) + esq[code];
        if (dist < bestd || (dist == bestd && code < bestk)) { bestd = dist; bestk = code; }
      }
    }
    // wave argmin + lowest-k tie-break (result lands in all lanes)
    #pragma unroll
    for (int off = 1; off < 64; off <<= 1) {
      float d2 = __shfl_xor(bestd, off, 64);
      int   k2 = __shfl_xor(bestk, off, 64);
      if (d2 < bestd || (d2 == bestd && k2 < bestk)) { bestd = d2; bestk = k2; }
    }
    const int bk = bestk;

    // gather quantized row + commitment loss partial
    float4 ev = ((const float4*)(ebase + (size_t)bk * DSUB))[lane];
    float4 zv = ((const float4*)(z + (size_t)row * DSUB))[lane];
    ((float4*)(out + (size_t)row * DSUB))[lane] = ev;
    float dx = zv.x - ev.x, dy = zv.y - ev.y, dz = zv.z - ev.z, dw = zv.w - ev.w;
    float d = dx * dx + dy * dy + dz * dz + dw * dw;
    #pragma unroll
    for (int off = 32; off; off >>= 1) d += __shfl_xor(d, off, 64);
    lossacc += d;
    if (lane == 0) {
      out[IDX_OFF + row] = (float)bk;
      atomicAdd(&counts[n * KCODES + bk], 1);
    }
  }
  if (lane == 0) atomicAdd(loss, lossacc);
}

// ------------------------------------------------------------ final kernel
__global__ void final_kernel(const int* __restrict__ counts, const float* __restrict__ loss,
                             float* __restrict__ out) {
  __shared__ float red[256];
  float h = 0.0f;
  for (int k = threadIdx.x; k < KCODES; k += 256) {
    float p = (float)(counts[k] + counts[KCODES + k]) * (1.0f / 16384.0f);
    h -= p * logf(p + 1e-10f);
  }
  red[threadIdx.x] = h;
  __syncthreads();
  for (int s = 128; s; s >>= 1) {
    if (threadIdx.x < s) red[threadIdx.x] += red[threadIdx.x + s];
    __syncthreads();
  }
  if (threadIdx.x == 0) {
    out[LOSS_OFF + 0] = 0.25f * loss[0] * (1.0f / (float)QUANT_N);
    out[LOSS_OFF + 1] = 0.0f;
    out[LOSS_OFF + 2] = expf(red[0]);
  }
}

extern "C" void kernel_launch(void* const* d_in, const int* in_sizes, int n_in,
                              void* d_out, int out_size, void* d_ws, size_t ws_size,
                              hipStream_t stream) {
  const float* z   = (const float*)d_in[0];
  const float* emb = (const float*)d_in[1];
  float* out = (float*)d_out;
  char*  ws  = (char*)d_ws;

  float* e_sq   = (float*)(ws + WS_ESQ);
  float* z_sq   = (float*)(ws + WS_ZSQ);
  int*   counts = (int*)(ws + WS_COUNTS);
  float* loss   = (float*)(ws + WS_LOSS);
  unsigned short* zbf = (unsigned short*)(ws + WS_ZBF);
  unsigned short* ebf = (unsigned short*)(ws + WS_EBF);
  __half* tmbuf = (__half*)(ws + WS_TM);

  hipMemsetAsync(ws + WS_COUNTS, 0, 65536 + 16, stream);
  prep_kernel<<<2048, 256, 0, stream>>>(z, emb, e_sq, z_sq, zbf, ebf);
  dim3 gA(32, 16, 2);
  passA_kernel<<<gA, 256, 0, stream>>>(zbf, ebf, e_sq, tmbuf);
  passB_kernel<<<2048, 256, 0, stream>>>(z, emb, e_sq, z_sq, tmbuf, out, counts, loss);
  final_kernel<<<1, 256, 0, stream>>>(counts, loss, out);
}

// Round 8
// 305.127 us; speedup vs baseline: 1.0540x; 1.0540x over previous
//
#include <hip/hip_runtime.h>
#include <hip/hip_fp16.h>

// VQ codebook quantization, MI355X.
//   prep:   fp32->bf16 fragment repack + norms + all zero-inits (no memsets).
//   passA:  barrier-free LDS-free bf16 MFMA -> per-(row,16-code-window) minima.
//   passB1: stream tm, per-row min+EPS ballot -> (row,win) pair queue.
//   passB2: wave per pair: exact fp32 rescore, 64-bit atomicMin winner
//           (dist_bits<<32|k: exact reference value + lowest-k ties).
//   passB3: wave per 8 rows: gather quantized, indices, counts, loss partials.
//   final:  perplexity + losses.
// B=8192, d_latent=512, ncb=2, K=8192, d_sub=256.

#define KCODES 8192
#define DSUB   256
#define BROWS  8192
#define NROWS  16384
#define NWIN   512

#define QUANT_N  (BROWS * 512)
#define IDX_OFF  QUANT_N
#define LOSS_OFF (QUANT_N + NROWS)

// ws layout (bytes)
#define WS_ESQ     0          // 16384 f32
#define WS_ZSQ     65536      // 16384 f32
#define WS_COUNTS  131072     // 16384 i32   (zeroed in prep)
#define WS_WINNER  196608     // 16384 u64   (0xFF.. in prep)
#define WS_LOSSARR 327680     // 2048 f32    (every slot written by passB3)
#define WS_QTAIL   335872     // 1 u32       (zeroed in prep)
#define WS_ZBF     1048576    // [2][8192][256] bf16 = 8 MB, fragment layout
#define WS_QUEUE   1048576    // u32 pairs — REUSES zbf (dead after passA)
#define QCAP       2000000
#define WS_EBF     9437184    // [2][8192][256] bf16 = 8 MB, fragment layout
#define WS_TM      17825792   // [2][8192][512] fp16 = 16 MB

#define EPS 2.5e-4f

// Fragment layout (elements, per codebook): row r, element k ->
//   (r>>4)*4096 + (k>>5)*512 + ((k>>3)&3)*128 + (r&15)*8 + (k&7)

typedef __attribute__((ext_vector_type(8))) short short8;
typedef __attribute__((ext_vector_type(8))) unsigned short ushort8v;
typedef __attribute__((ext_vector_type(4))) float floatx4;

__device__ inline unsigned short f2bf(float f) {
  unsigned u = __float_as_uint(f);
  return (unsigned short)((u + 0x7FFFu + ((u >> 16) & 1u)) >> 16);
}

// ------------------------------------------------------------ prep kernel
// 1024 blocks x 256. Init section (blocks 0..64) + 4 row-pair iterations/wave.
__global__ void prep_kernel(const float* __restrict__ z, const float* __restrict__ e,
                            float* __restrict__ e_sq, float* __restrict__ z_sq,
                            unsigned short* __restrict__ zbf, unsigned short* __restrict__ ebf,
                            int* __restrict__ counts, unsigned long long* __restrict__ winner,
                            unsigned* __restrict__ qtail) {
  int t = blockIdx.x * 256 + threadIdx.x;
  if (t < 16384) { counts[t] = 0; winner[t] = ~0ull; }
  if (t == 16384) *qtail = 0;

  int gw  = blockIdx.x * 4 + (threadIdx.x >> 6);  // 0..4095
  int l   = threadIdx.x & 63;
  int sub = l >> 5;
  int l32 = l & 31;
  for (int i = 0; i < 4; ++i) {
    int row = i * 8192 + gw * 2 + sub;            // 0..32767 (i<2: emb, else z)
    const float* src;
    unsigned short* dst;
    int r;
    float* sq;
    int sqi;
    if (row < NROWS) {
      src = e + (size_t)row * DSUB;
      dst = ebf; r = row; sq = e_sq; sqi = row;
    } else {
      int rz = row - NROWS;
      int n = rz & 1, b = rz >> 1;
      src = z + (size_t)rz * DSUB;
      dst = zbf + (size_t)n * 2097152; r = b; sq = z_sq; sqi = rz;
    }
    float4 v0 = ((const float4*)src)[2 * l32];
    float4 v1 = ((const float4*)src)[2 * l32 + 1];
    ushort8v o;
    o[0] = f2bf(v0.x); o[1] = f2bf(v0.y); o[2] = f2bf(v0.z); o[3] = f2bf(v0.w);
    o[4] = f2bf(v1.x); o[5] = f2bf(v1.y); o[6] = f2bf(v1.z); o[7] = f2bf(v1.w);
    size_t off = (size_t)(r >> 4) * 4096 + (l32 >> 2) * 512 + (l32 & 3) * 128 + (r & 15) * 8;
    *(ushort8v*)(dst + off) = o;
    float s = v0.x * v0.x + v0.y * v0.y + v0.z * v0.z + v0.w * v0.w
            + v1.x * v1.x + v1.y * v1.y + v1.z * v1.z + v1.w * v1.w;
    #pragma unroll
    for (int off2 = 16; off2; off2 >>= 1) s += __shfl_down(s, off2, 32);
    if (l32 == 0) sq[sqi] = s;
  }
}

// ------------------------------------------------------------ pass A (MFMA)
__global__ __launch_bounds__(256, 2)
void passA_kernel(const unsigned short* __restrict__ zbf, const unsigned short* __restrict__ ebf,
                  const float* __restrict__ e_sq, __half* __restrict__ tm) {
  const int n    = blockIdx.z;
  const int w    = threadIdx.x >> 6, lane = threadIdx.x & 63;
  const int quad = lane >> 4, c16 = lane & 15;
  const int cb   = blockIdx.x * 256 + w * 64;
  const int rg   = blockIdx.y * 512;

  const unsigned short* en = ebf + (size_t)n * 2097152;
  const unsigned short* zn = zbf + (size_t)n * 2097152;
  const float* esq = e_sq + n * KCODES;
  __half* tmn = tm + (size_t)n * (BROWS * NWIN);

  short8 areg[8][4];
  #pragma unroll
  for (int k0 = 0; k0 < 8; ++k0)
    #pragma unroll
    for (int mf = 0; mf < 4; ++mf)
      areg[k0][mf] = *(const short8*)(en + (size_t)((cb >> 4) + mf) * 4096 + k0 * 512 + lane * 8);

  float eq[4][4];
  #pragma unroll
  for (int mf = 0; mf < 4; ++mf) {
    int kb = cb + mf * 16 + quad * 4;
    #pragma unroll
    for (int i = 0; i < 4; ++i) eq[mf][i] = esq[kb + i];
  }

  for (int nt = 0; nt < 8; ++nt) {
    const int rowbase = rg + nt * 64;

    floatx4 acc[4][4];
    #pragma unroll
    for (int i = 0; i < 4; ++i)
      #pragma unroll
      for (int j = 0; j < 4; ++j) acc[i][j] = (floatx4){0.f, 0.f, 0.f, 0.f};

    #pragma unroll
    for (int k0 = 0; k0 < 8; ++k0) {
      short8 b[4];
      #pragma unroll
      for (int nf = 0; nf < 4; ++nf)
        b[nf] = *(const short8*)(zn + (size_t)((rowbase >> 4) + nf) * 4096 + k0 * 512 + lane * 8);
      #pragma unroll
      for (int mf = 0; mf < 4; ++mf)
        #pragma unroll
        for (int nf = 0; nf < 4; ++nf)
          acc[mf][nf] = __builtin_amdgcn_mfma_f32_16x16x32_bf16(areg[k0][mf], b[nf], acc[mf][nf], 0, 0, 0);
    }

    #pragma unroll
    for (int nf = 0; nf < 4; ++nf) {
      float vm[4];
      #pragma unroll
      for (int mf = 0; mf < 4; ++mf) {
        float v = eq[mf][0] - 2.0f * acc[mf][nf][0];
        v = fminf(v, eq[mf][1] - 2.0f * acc[mf][nf][1]);
        v = fminf(v, eq[mf][2] - 2.0f * acc[mf][nf][2]);
        v = fminf(v, eq[mf][3] - 2.0f * acc[mf][nf][3]);
        v = fminf(v, __shfl_xor(v, 16, 64));
        v = fminf(v, __shfl_xor(v, 32, 64));
        vm[mf] = v;
      }
      if (quad == 0) {
        int zr = rowbase + nf * 16 + c16;
        ushort4 o;
        o.x = __half_as_ushort(__float2half(vm[0]));
        o.y = __half_as_ushort(__float2half(vm[1]));
        o.z = __half_as_ushort(__float2half(vm[2]));
        o.w = __half_as_ushort(__float2half(vm[3]));
        *(ushort4*)&tmn[(size_t)zr * NWIN + (cb >> 4)] = o;
      }
    }
  }
}

// ------------------------------------------------------------ passB1 (select)
// 512 blocks x 4 waves; wave owns 8 consecutive rows. Batched tm loads, per-row
// min+EPS ballot, pairs buffered in LDS, ONE queue atomic per block.
__global__ __launch_bounds__(256)
void passB1_kernel(const __half* __restrict__ tm, unsigned* __restrict__ queue,
                   unsigned* __restrict__ qtail) {
  __shared__ unsigned buf[4][512];
  __shared__ unsigned wcnt[4];
  __shared__ unsigned pre[4];
  __shared__ unsigned base_sh;

  const int w = threadIdx.x >> 6, lane = threadIdx.x & 63;
  const int gw = blockIdx.x * 4 + w;
  const int r0 = gw * 8;                      // rows r0..r0+8 (rz indexing)

  uint4 tq[8];
  #pragma unroll
  for (int i = 0; i < 8; ++i) {
    int row = r0 + i;
    int n = row & 1, b = row >> 1;
    tq[i] = *(const uint4*)(tm + ((size_t)n * BROWS + b) * NWIN + lane * 8);
  }

  unsigned cnt = 0;
  #pragma unroll
  for (int i = 0; i < 8; ++i) {
    int row = r0 + i;
    float t[8];
    __half2 h;
    h = *(__half2*)&tq[i].x; t[0] = __low2float(h); t[1] = __high2float(h);
    h = *(__half2*)&tq[i].y; t[2] = __low2float(h); t[3] = __high2float(h);
    h = *(__half2*)&tq[i].z; t[4] = __low2float(h); t[5] = __high2float(h);
    h = *(__half2*)&tq[i].w; t[6] = __low2float(h); t[7] = __high2float(h);
    float mv = t[0];
    #pragma unroll
    for (int j = 1; j < 8; ++j) mv = fminf(mv, t[j]);
    #pragma unroll
    for (int off = 32; off; off >>= 1) mv = fminf(mv, __shfl_xor(mv, off, 64));
    const float thr = mv + EPS;
    #pragma unroll
    for (int j = 0; j < 8; ++j) {
      unsigned long long mb = __ballot(t[j] <= thr);
      while (mb) {
        int src = __ffsll(mb) - 1;
        mb &= mb - 1;
        if (cnt < 512) {
          if (lane == 0) buf[w][cnt] = ((unsigned)row << 16) | (unsigned)(src * 8 + j);
          ++cnt;
        }
      }
    }
  }
  if (lane == 0) wcnt[w] = cnt;
  __syncthreads();
  if (threadIdx.x == 0) {
    unsigned s = 0;
    #pragma unroll
    for (int i = 0; i < 4; ++i) { pre[i] = s; s += wcnt[i]; }
    base_sh = atomicAdd(qtail, s);
  }
  __syncthreads();
  unsigned base = base_sh + pre[w];
  for (unsigned i = lane; i < wcnt[w]; i += 64)
    if (base + i < QCAP) queue[base + i] = buf[w][i];
}

// ------------------------------------------------------------ passB2 (rescore)
// Grid-stride waves over (row,window) pairs. Exact fp32 rescore, atomicMin64.
__global__ __launch_bounds__(256)
void passB2_kernel(const float* __restrict__ z, const float* __restrict__ emb,
                   const float* __restrict__ e_sq, const float* __restrict__ z_sq,
                   const unsigned* __restrict__ queue, const unsigned* __restrict__ qtail,
                   unsigned long long* __restrict__ winner) {
  const int w = threadIdx.x >> 6, lane = threadIdx.x & 63;
  const int q = lane & 3, g = lane >> 2;
  unsigned qlen = *qtail;
  if (qlen > QCAP) qlen = QCAP;
  const unsigned nw = gridDim.x * 4;

  for (unsigned idx = blockIdx.x * 4 + w; idx < qlen; idx += nw) {
    unsigned e = queue[idx];
    int row = e >> 16, win = e & 0xFFFF;
    int n = row & 1;
    int code = win * 16 + g;
    const float* ebase = emb + (size_t)n * KCODES * DSUB;
    const float4* ep = (const float4*)(ebase + (size_t)code * DSUB + q * 64);
    const float4* zp = (const float4*)(z + (size_t)row * DSUB + q * 64);
    float s = 0.f;
    #pragma unroll
    for (int u = 0; u < 16; ++u) {
      float4 ev = ep[u], zv = zp[u];
      s += ev.x * zv.x; s += ev.y * zv.y; s += ev.z * zv.z; s += ev.w * zv.w;
    }
    s += __shfl_xor(s, 1, 64);
    s += __shfl_xor(s, 2, 64);
    float bd = (z_sq[row] - 2.0f * s) + e_sq[n * KCODES + code];
    int   bk = code;
    #pragma unroll
    for (int off = 4; off < 64; off <<= 1) {
      float d2 = __shfl_xor(bd, off, 64);
      int   k2 = __shfl_xor(bk, off, 64);
      if (d2 < bd || (d2 == bd && k2 < bk)) { bd = d2; bk = k2; }
    }
    if (lane == 0)
      atomicMin(&winner[row], ((unsigned long long)__float_as_uint(bd) << 32) | (unsigned)bk);
  }
}

// ------------------------------------------------------------ passB3 (gather)
// 512 blocks x 4 waves; wave per 8 rows, 2-row batched loads, loss -> array.
__global__ __launch_bounds__(256)
void passB3_kernel(const float* __restrict__ z, const float* __restrict__ emb,
                   const unsigned long long* __restrict__ winner, float* __restrict__ out,
                   int* __restrict__ counts, float* __restrict__ lossarr) {
  const int w = threadIdx.x >> 6, lane = threadIdx.x & 63;
  const int gw = blockIdx.x * 4 + w;        // 0..2047
  float lossacc = 0.f;

  for (int i = 0; i < 4; ++i) {
    int row0 = gw * 8 + i * 2;
    int bk0 = (int)(unsigned)winner[row0];
    int bk1 = (int)(unsigned)winner[row0 + 1];
    const float* eb0 = emb + ((size_t)(row0 & 1) * KCODES + bk0) * DSUB;
    const float* eb1 = emb + ((size_t)((row0 + 1) & 1) * KCODES + bk1) * DSUB;
    float4 ev0 = ((const float4*)eb0)[lane];
    float4 ev1 = ((const float4*)eb1)[lane];
    float4 zv0 = ((const float4*)(z + (size_t)row0 * DSUB))[lane];
    float4 zv1 = ((const float4*)(z + (size_t)(row0 + 1) * DSUB))[lane];
    ((float4*)(out + (size_t)row0 * DSUB))[lane] = ev0;
    ((float4*)(out + (size_t)(row0 + 1) * DSUB))[lane] = ev1;
    float dx = zv0.x - ev0.x, dy = zv0.y - ev0.y, dz = zv0.z - ev0.z, dw = zv0.w - ev0.w;
    lossacc += dx * dx + dy * dy + dz * dz + dw * dw;
    dx = zv1.x - ev1.x; dy = zv1.y - ev1.y; dz = zv1.z - ev1.z; dw = zv1.w - ev1.w;
    lossacc += dx * dx + dy * dy + dz * dz + dw * dw;
    if (lane == 0) {
      out[IDX_OFF + row0] = (float)bk0;
      out[IDX_OFF + row0 + 1] = (float)bk1;
      atomicAdd(&counts[(row0 & 1) * KCODES + bk0], 1);
      atomicAdd(&counts[((row0 + 1) & 1) * KCODES + bk1], 1);
    }
  }
  #pragma unroll
  for (int off = 32; off; off >>= 1) lossacc += __shfl_xor(lossacc, off, 64);
  if (lane == 0) lossarr[gw] = lossacc;
}

// ------------------------------------------------------------ final kernel
__global__ void final_kernel(const int* __restrict__ counts, const float* __restrict__ lossarr,
                             float* __restrict__ out) {
  __shared__ float redh[256];
  __shared__ float redl[256];
  float h = 0.0f, ls = 0.0f;
  for (int k = threadIdx.x; k < KCODES; k += 256) {
    float p = (float)(counts[k] + counts[KCODES + k]) * (1.0f / 16384.0f);
    h -= p * logf(p + 1e-10f);
  }
  for (int k = threadIdx.x; k < 2048; k += 256) ls += lossarr[k];
  redh[threadIdx.x] = h;
  redl[threadIdx.x] = ls;
  __syncthreads();
  for (int s = 128; s; s >>= 1) {
    if (threadIdx.x < s) {
      redh[threadIdx.x] += redh[threadIdx.x + s];
      redl[threadIdx.x] += redl[threadIdx.x + s];
    }
    __syncthreads();
  }
  if (threadIdx.x == 0) {
    out[LOSS_OFF + 0] = 0.25f * redl[0] * (1.0f / (float)QUANT_N);
    out[LOSS_OFF + 1] = 0.0f;
    out[LOSS_OFF + 2] = expf(redh[0]);
  }
}

extern "C" void kernel_launch(void* const* d_in, const int* in_sizes, int n_in,
                              void* d_out, int out_size, void* d_ws, size_t ws_size,
                              hipStream_t stream) {
  const float* z   = (const float*)d_in[0];
  const float* emb = (const float*)d_in[1];
  float* out = (float*)d_out;
  char*  ws  = (char*)d_ws;

  float* e_sq   = (float*)(ws + WS_ESQ);
  float* z_sq   = (float*)(ws + WS_ZSQ);
  int*   counts = (int*)(ws + WS_COUNTS);
  unsigned long long* winner = (unsigned long long*)(ws + WS_WINNER);
  float* lossarr = (float*)(ws + WS_LOSSARR);
  unsigned* qtail = (unsigned*)(ws + WS_QTAIL);
  unsigned short* zbf = (unsigned short*)(ws + WS_ZBF);
  unsigned short* ebf = (unsigned short*)(ws + WS_EBF);
  unsigned* queue = (unsigned*)(ws + WS_QUEUE);
  __half* tmbuf = (__half*)(ws + WS_TM);

  prep_kernel<<<1024, 256, 0, stream>>>(z, emb, e_sq, z_sq, zbf, ebf, counts, winner, qtail);
  dim3 gA(32, 16, 2);
  passA_kernel<<<gA, 256, 0, stream>>>(zbf, ebf, e_sq, tmbuf);
  passB1_kernel<<<512, 256, 0, stream>>>(tmbuf, queue, qtail);
  passB2_kernel<<<512, 256, 0, stream>>>(z, emb, e_sq, z_sq, queue, qtail, winner);
  passB3_kernel<<<512, 256, 0, stream>>>(z, emb, winner, out, counts, lossarr);
  final_kernel<<<1, 256, 0, stream>>>(counts, lossarr, out);
}